// Round 1
// baseline (196.750 us; speedup 1.0000x reference)
//
#include <hip/hip_runtime.h>
#include <stdint.h>

// Problem constants (TransformerLayer: N=6144, D=512, B=16, NMAX=512, H=8, HD=64)
#define N_NODES 6144
#define DIM 512
#define NGRAPH 16
#define NHEAD 8
#define EPSV 1e-5f

typedef unsigned short u16;
typedef short s16x8 __attribute__((ext_vector_type(8)));
typedef __bf16 bf16x8 __attribute__((ext_vector_type(8)));
typedef float f32x4 __attribute__((ext_vector_type(4)));

__device__ __forceinline__ u16 f2bf(float f) {
  union { float f; unsigned u; } c{f};
  unsigned u = c.u;
  return (u16)((u + 0x7fffu + ((u >> 16) & 1u)) >> 16);  // RNE
}

__device__ __forceinline__ f32x4 mfma16(s16x8 a, s16x8 b, f32x4 c) {
  return __builtin_amdgcn_mfma_f32_16x16x32_bf16(
      __builtin_bit_cast(bf16x8, a), __builtin_bit_cast(bf16x8, b), c, 0, 0, 0);
}

__device__ __forceinline__ void gload_lds16(const void* g, void* l) {
  __builtin_amdgcn_global_load_lds(
      (const __attribute__((address_space(1))) unsigned int*)g,
      (__attribute__((address_space(3))) unsigned int*)l, 16, 0, 0);
}

// ---------------------------------------------------------------- starts
__global__ void starts_kernel(const int* __restrict__ batch, int* __restrict__ starts) {
  int g = threadIdx.x;
  if (g > NGRAPH) return;
  if (g == NGRAPH) { starts[g] = N_NODES; return; }
  int lo = 0, hi = N_NODES;
  while (lo < hi) { int mid = (lo + hi) >> 1; if (batch[mid] < g) lo = mid + 1; else hi = mid; }
  starts[g] = lo;
}

// ------------------------------------------------- weight transpose f32->bf16
// src[R][C] f32 -> dst[C][R] bf16
__global__ void transpose_kernel(const float* __restrict__ src, u16* __restrict__ dst,
                                 int R, int C) {
  __shared__ float tile[32][33];
  int c0 = blockIdx.x * 32, r0 = blockIdx.y * 32;
  int tx = threadIdx.x & 31, ty = threadIdx.x >> 5;
#pragma unroll
  for (int i = 0; i < 32; i += 8) tile[ty + i][tx] = src[(size_t)(r0 + ty + i) * C + c0 + tx];
  __syncthreads();
#pragma unroll
  for (int i = 0; i < 32; i += 8) dst[(size_t)(c0 + ty + i) * R + r0 + tx] = f2bf(tile[tx][ty + i]);
}

__global__ void cvt_bf16_kernel(const float* __restrict__ src, u16* __restrict__ dst, int n4) {
  int i = blockIdx.x * 256 + threadIdx.x;
  if (i < n4) {
    float4 v = ((const float4*)src)[i];
    ushort4 o = make_ushort4(f2bf(v.x), f2bf(v.y), f2bf(v.z), f2bf(v.w));
    ((ushort4*)dst)[i] = o;
  }
}

__global__ void zero_kernel(uint4* __restrict__ p, int n) {
  int i = blockIdx.x * 256 + threadIdx.x;
  if (i < n) p[i] = make_uint4(0, 0, 0, 0);
}

// ---------------------------------------------------------------- GEMM
// C[i][j] = sum_k A[i][k] * Bt[j][k]   (A,Bt bf16 row-major, acc fp32)
// EPI 0: QKV -> q_perm[node][h*64+f], k_perm same, vt[b][h][f][m]  (+bias)
// EPI 1: of = acc + bias + res                (fp32)
// EPI 2: ob = relu(acc + bias)                (bf16)
// EPI 3: of = acc + bias + res*st.x + st.y    (fp32, BN1-recompute residual)
template <int BM, int BN, int EPI>
__global__ __launch_bounds__(256, 2) void gemm_kernel(
    const u16* __restrict__ A, const u16* __restrict__ Bt,
    const float* __restrict__ bias0, const float* __restrict__ bias1,
    const float* __restrict__ bias2, const float* __restrict__ res,
    const float2* __restrict__ stats, const int* __restrict__ batch,
    const int* __restrict__ starts, u16* __restrict__ oq, u16* __restrict__ ok,
    u16* __restrict__ ovt, float* __restrict__ of, u16* __restrict__ ob,
    int M, int N, int K) {
  constexpr int NW_M = (BM >= 128) ? 2 : 1;
  constexpr int NW_N = 4 / NW_M;
  constexpr int WM = BM / NW_M, WN = BN / NW_N;
  constexpr int FM = WM / 16, FN = WN / 16;
  __shared__ __align__(16) u16 As[BM * 32];
  __shared__ __align__(16) u16 Bs[BN * 32];
  const int tid = threadIdx.x;
  const int lane = tid & 63, wv = tid >> 6;
  const int wm = wv / NW_N, wn = wv % NW_N;
  const int row0 = blockIdx.y * BM, col0 = blockIdx.x * BN;

  f32x4 acc[FM][FN] = {};
  int a_off[FM], b_off[FN];
#pragma unroll
  for (int fm = 0; fm < FM; ++fm) {
    int r = wm * WM + fm * 16 + (lane & 15);
    a_off[fm] = r * 32 + (((lane >> 4) ^ ((r >> 1) & 3)) << 3);
  }
#pragma unroll
  for (int fn = 0; fn < FN; ++fn) {
    int r = wn * WN + fn * 16 + (lane & 15);
    b_off[fn] = r * 32 + (((lane >> 4) ^ ((r >> 1) & 3)) << 3);
  }

  for (int k0 = 0; k0 < K; k0 += 32) {
    __syncthreads();
#pragma unroll
    for (int is = 0; is < BM / 64; ++is) {
      int s = is * 256 + tid;
      int r = s >> 2;
      int cl = (s & 3) ^ ((r >> 1) & 3);  // pre-swizzled source (involution)
      gload_lds16(A + (size_t)(row0 + r) * K + k0 + cl * 8,
                  (void*)(As + (size_t)(is * 256 + (tid & ~63)) * 8));
    }
#pragma unroll
    for (int is = 0; is < BN / 64; ++is) {
      int s = is * 256 + tid;
      int r = s >> 2;
      int cl = (s & 3) ^ ((r >> 1) & 3);
      gload_lds16(Bt + (size_t)(col0 + r) * K + k0 + cl * 8,
                  (void*)(Bs + (size_t)(is * 256 + (tid & ~63)) * 8));
    }
    __syncthreads();
    s16x8 af[FM], bfv[FN];
#pragma unroll
    for (int fm = 0; fm < FM; ++fm) af[fm] = *(const s16x8*)(As + a_off[fm]);
#pragma unroll
    for (int fn = 0; fn < FN; ++fn) bfv[fn] = *(const s16x8*)(Bs + b_off[fn]);
#pragma unroll
    for (int fm = 0; fm < FM; ++fm)
#pragma unroll
      for (int fn = 0; fn < FN; ++fn)
        acc[fm][fn] = mfma16(af[fm], bfv[fn], acc[fm][fn]);
  }

  // epilogue: C elem (row=(lane>>4)*4+ii, col=lane&15) per 16x16 frag
#pragma unroll
  for (int fn = 0; fn < FN; ++fn) {
    const int j = col0 + wn * WN + fn * 16 + (lane & 15);
#pragma unroll
    for (int fm = 0; fm < FM; ++fm) {
      const int ibase = row0 + wm * WM + fm * 16 + ((lane >> 4) << 2);
      if constexpr (EPI == 0) {
        const int which = j >> 9, jj = j & 511;
        const int hh = jj & 7, f = jj >> 3;
        const float bj = (which == 0) ? bias0[jj] : (which == 1) ? bias1[jj] : bias2[jj];
#pragma unroll
        for (int ii = 0; ii < 4; ++ii) {
          int i = ibase + ii;
          u16 v = f2bf(acc[fm][fn][ii] + bj);
          if (which == 0) oq[(size_t)i * 512 + hh * 64 + f] = v;
          else if (which == 1) ok[(size_t)i * 512 + hh * 64 + f] = v;
          else {
            int b = batch[i], m = i - starts[b];
            ovt[(((size_t)(b * 8 + hh)) * 64 + f) * 512 + m] = v;
          }
        }
      } else if constexpr (EPI == 1) {
        const float bj = bias0[j];
#pragma unroll
        for (int ii = 0; ii < 4; ++ii) {
          int i = ibase + ii;
          of[(size_t)i * N + j] = acc[fm][fn][ii] + bj + res[(size_t)i * N + j];
        }
      } else if constexpr (EPI == 2) {
        const float bj = bias0[j];
#pragma unroll
        for (int ii = 0; ii < 4; ++ii) {
          int i = ibase + ii;
          float v = acc[fm][fn][ii] + bj;
          ob[(size_t)i * N + j] = f2bf(v > 0.f ? v : 0.f);
        }
      } else {
        const float bj = bias0[j];
        const float2 st = stats[j];
#pragma unroll
        for (int ii = 0; ii < 4; ++ii) {
          int i = ibase + ii;
          of[(size_t)i * N + j] = acc[fm][fn][ii] + bj + res[(size_t)i * N + j] * st.x + st.y;
        }
      }
    }
  }
}

// ---------------------------------------------------------------- attention
// out[n] = sum_m exp(K[n]·Q[m]/8) V[m] / sum_m exp(...)   (per graph b, head hh)
// Scores are O(1) -> no max subtraction needed. m>=nb masked to P=0.
__global__ __launch_bounds__(256, 2) void attn_kernel(
    const u16* __restrict__ qp, const u16* __restrict__ kp,
    const u16* __restrict__ vt, const int* __restrict__ starts,
    u16* __restrict__ av) {
  __shared__ __align__(16) u16 Qs[32 * 64];   // [m][f], 8-chunk XOR swizzle
  __shared__ __align__(16) u16 Vs[64 * 32];   // [f][m], 4-chunk XOR swizzle
  __shared__ __align__(16) u16 Ps[4][512];    // per-wave P tile [16][32]
  const int idx = blockIdx.x;
  const int rb = idx & 7, hh = (idx >> 3) & 7, b = idx >> 6;
  const int base = starts[b], nb = starts[b + 1] - base;
  const int r0 = rb * 64;
  if (r0 >= nb) return;
  const int tid = threadIdx.x, lane = tid & 63, wv = tid >> 6;
  const int rloc = r0 + wv * 16 + (lane & 15);
  const u16* krow = kp + (size_t)(base + rloc) * 512 + hh * 64 + ((lane >> 4) << 3);
  s16x8 ak0 = *(const s16x8*)(krow);
  s16x8 ak1 = *(const s16x8*)(krow + 32);
  f32x4 acc_av[4] = {};
  float rs[4] = {0.f, 0.f, 0.f, 0.f};
  const u16* vhead = vt + (size_t)(b * 8 + hh) * 64 * 512;
  u16* Pw = Ps[wv];

  for (int m0 = 0; m0 < nb; m0 += 32) {
    __syncthreads();
    {  // stage Q tile 32x64
      int r = tid >> 3, cl = (tid & 7) ^ (r & 7);
      gload_lds16(qp + (size_t)(base + m0 + r) * 512 + hh * 64 + cl * 8,
                  (void*)(Qs + (size_t)(tid & ~63) * 8));
    }
    {  // stage V^T tile 64x32
      int f = tid >> 2, cl = (tid & 3) ^ ((f >> 1) & 3);
      gload_lds16(vhead + (size_t)f * 512 + m0 + cl * 8,
                  (void*)(Vs + (size_t)(tid & ~63) * 8));
    }
    __syncthreads();
#pragma unroll
    for (int ch = 0; ch < 2; ++ch) {
      f32x4 s = {};
#pragma unroll
      for (int kc = 0; kc < 2; ++kc) {
        const int mr = ch * 16 + (lane & 15);
        const int chunk = kc * 4 + (lane >> 4);
        s16x8 bq = *(const s16x8*)(Qs + mr * 64 + ((chunk ^ (mr & 7)) << 3));
        s = mfma16(kc == 0 ? ak0 : ak1, bq, s);
      }
      const int mg = m0 + ch * 16 + (lane & 15);
      const bool valid = mg < nb;
      const int c = ch * 16 + (lane & 15);
#pragma unroll
      for (int ii = 0; ii < 4; ++ii) {
        float pv = valid ? __expf(s[ii] * 0.125f) : 0.f;
        rs[ii] += pv;
        const int r = ((lane >> 4) << 2) + ii;
        Pw[r * 32 + (((c >> 3) ^ ((r >> 1) & 3)) << 3) + (c & 7)] = f2bf(pv);
      }
    }
    // read P back as A-fragment (same wave: compiler orders via lgkmcnt)
    const int pr = lane & 15;
    s16x8 pa = *(const s16x8*)(Pw + pr * 32 + (((lane >> 4) ^ ((pr >> 1) & 3)) << 3));
#pragma unroll
    for (int fb = 0; fb < 4; ++fb) {
      const int fr = fb * 16 + (lane & 15);
      s16x8 bv = *(const s16x8*)(Vs + fr * 32 + (((lane >> 4) ^ ((fr >> 1) & 3)) << 3));
      acc_av[fb] = mfma16(pa, bv, acc_av[fb]);
    }
  }
#pragma unroll
  for (int ii = 0; ii < 4; ++ii) {
    float v = rs[ii];
    v += __shfl_xor(v, 1); v += __shfl_xor(v, 2);
    v += __shfl_xor(v, 4); v += __shfl_xor(v, 8);
    rs[ii] = 1.f / v;
  }
#pragma unroll
  for (int ii = 0; ii < 4; ++ii) {
    const int rl = r0 + wv * 16 + ((lane >> 4) << 2) + ii;
    if (rl < nb) {
      const size_t node = base + rl;
#pragma unroll
      for (int fb = 0; fb < 4; ++fb) {
        const int f = fb * 16 + (lane & 15);
        av[node * 512 + f * 8 + hh] = f2bf(acc_av[fb][ii] * rs[ii]);  // model layout d=f*8+h
      }
    }
  }
}

// ---------------------------------------------------------------- batchnorm
__global__ void bn_part_kernel(const float* __restrict__ x, float4* __restrict__ part) {
  const int p = blockIdx.x, t = threadIdx.x;
  float s0 = 0, q0 = 0, s1 = 0, q1 = 0;
  const int r0 = p * 128;
  for (int r = r0; r < r0 + 128; ++r) {
    float2 v = ((const float2*)x)[(size_t)r * 256 + t];
    s0 += v.x; q0 += v.x * v.x; s1 += v.y; q1 += v.y * v.y;
  }
  part[p * 256 + t] = make_float4(s0, q0, s1, q1);
}

__global__ void bn_fin_kernel(const float4* __restrict__ part, const float* __restrict__ g,
                              const float* __restrict__ be, float2* __restrict__ stats) {
  const int t = threadIdx.x;
  float s0 = 0, q0 = 0, s1 = 0, q1 = 0;
  for (int p = 0; p < 48; ++p) {
    float4 v = part[p * 256 + t];
    s0 += v.x; q0 += v.y; s1 += v.z; q1 += v.w;
  }
  const float inv = 1.f / (float)N_NODES;
  {
    int c = 2 * t;
    float m = s0 * inv, var = q0 * inv - m * m;
    float sc = g[c] * rsqrtf(var + EPSV);
    stats[c] = make_float2(sc, be[c] - m * sc);
  }
  {
    int c = 2 * t + 1;
    float m = s1 * inv, var = q1 * inv - m * m;
    float sc = g[c] * rsqrtf(var + EPSV);
    stats[c] = make_float2(sc, be[c] - m * sc);
  }
}

__global__ void bn_apply_bf_kernel(const float* __restrict__ x, const float2* __restrict__ stats,
                                   u16* __restrict__ o) {
  const int i = (blockIdx.x * 256 + threadIdx.x) * 4;
  float4 v = *(const float4*)(x + i);
  const int c = i & 511;
  float2 sa = stats[c], sb = stats[c + 1], sc2 = stats[c + 2], sd = stats[c + 3];
  ushort4 r = make_ushort4(f2bf(v.x * sa.x + sa.y), f2bf(v.y * sb.x + sb.y),
                           f2bf(v.z * sc2.x + sc2.y), f2bf(v.w * sd.x + sd.y));
  *(ushort4*)(o + i) = r;
}

__global__ void bn_apply_f32_kernel(float* __restrict__ x, const float2* __restrict__ stats) {
  const int i = (blockIdx.x * 256 + threadIdx.x) * 4;
  float4 v = *(float4*)(x + i);
  const int c = i & 511;
  float2 sa = stats[c], sb = stats[c + 1], sc2 = stats[c + 2], sd = stats[c + 3];
  *(float4*)(x + i) = make_float4(v.x * sa.x + sa.y, v.y * sb.x + sb.y,
                                  v.z * sc2.x + sc2.y, v.w * sd.x + sd.y);
}

// ---------------------------------------------------------------- launch
extern "C" void kernel_launch(void* const* d_in, const int* in_sizes, int n_in,
                              void* d_out, int out_size, void* d_ws, size_t ws_size,
                              hipStream_t stream) {
  const float* h   = (const float*)d_in[0];
  const int* batch = (const int*)d_in[1];
  const float* Wq = (const float*)d_in[2];  const float* bq = (const float*)d_in[3];
  const float* Wk = (const float*)d_in[4];  const float* bk = (const float*)d_in[5];
  const float* Wv = (const float*)d_in[6];  const float* bv = (const float*)d_in[7];
  const float* Wo = (const float*)d_in[8];  const float* bo = (const float*)d_in[9];
  const float* g1 = (const float*)d_in[10]; const float* be1 = (const float*)d_in[11];
  const float* W1 = (const float*)d_in[12]; const float* b1v = (const float*)d_in[13];
  const float* W2 = (const float*)d_in[14]; const float* b2v = (const float*)d_in[15];
  const float* g2 = (const float*)d_in[16]; const float* be2 = (const float*)d_in[17];
  float* out = (float*)d_out;
  (void)in_sizes; (void)n_in; (void)out_size; (void)ws_size;

  char* ws = (char*)d_ws;
  size_t off = 0;
  auto alloc = [&](size_t bytes) -> void* {
    void* p = ws + off;
    off += (bytes + 255) & ~(size_t)255;
    return p;
  };
  int*    starts = (int*)alloc(17 * 4);
  float4* part   = (float4*)alloc((size_t)48 * 256 * sizeof(float4));
  float2* stats1 = (float2*)alloc(512 * sizeof(float2));
  float2* stats2 = (float2*)alloc(512 * sizeof(float2));
  u16* bt_qkv = (u16*)alloc((size_t)1536 * 512 * 2);
  u16* bt_o   = (u16*)alloc((size_t)512 * 512 * 2);
  u16* bt_1   = (u16*)alloc((size_t)1024 * 512 * 2);
  u16* bt_2   = (u16*)alloc((size_t)512 * 1024 * 2);
  u16* A0  = (u16*)alloc((size_t)N_NODES * 512 * 2);          // h bf16; reused as av
  u16* qp  = (u16*)alloc((size_t)(N_NODES + 64) * 512 * 2);   // reused (with kp) as x2
  u16* kp  = (u16*)alloc((size_t)(N_NODES + 64) * 512 * 2);
  u16* vtb = (u16*)alloc((size_t)NGRAPH * NHEAD * 64 * 512 * 2);
  float* x1 = (float*)alloc((size_t)N_NODES * 512 * 4);
  u16* x1n  = (u16*)alloc((size_t)N_NODES * 512 * 2);
  u16* av = A0;
  u16* x2 = qp;  // qp+kp = 12.7MB >= 12.6MB needed

  starts_kernel<<<1, 32, 0, stream>>>(batch, starts);
  transpose_kernel<<<dim3(16, 16), 256, 0, stream>>>(Wq, bt_qkv, 512, 512);
  transpose_kernel<<<dim3(16, 16), 256, 0, stream>>>(Wk, bt_qkv + 512 * 512, 512, 512);
  transpose_kernel<<<dim3(16, 16), 256, 0, stream>>>(Wv, bt_qkv + 2 * 512 * 512, 512, 512);
  transpose_kernel<<<dim3(16, 16), 256, 0, stream>>>(Wo, bt_o, 512, 512);
  transpose_kernel<<<dim3(32, 16), 256, 0, stream>>>(W1, bt_1, 512, 1024);
  transpose_kernel<<<dim3(16, 32), 256, 0, stream>>>(W2, bt_2, 1024, 512);
  cvt_bf16_kernel<<<3072, 256, 0, stream>>>(h, A0, N_NODES * 512 / 4);
  zero_kernel<<<2048, 256, 0, stream>>>((uint4*)vtb, NGRAPH * NHEAD * 64 * 512 * 2 / 16);

  gemm_kernel<128, 128, 0><<<dim3(12, 48), 256, 0, stream>>>(
      A0, bt_qkv, bq, bk, bv, nullptr, nullptr, batch, starts, qp, kp, vtb,
      nullptr, nullptr, N_NODES, 1536, 512);
  attn_kernel<<<NGRAPH * NHEAD * 8, 256, 0, stream>>>(qp, kp, vtb, starts, av);
  gemm_kernel<64, 128, 1><<<dim3(4, 96), 256, 0, stream>>>(
      av, bt_o, bo, nullptr, nullptr, h, nullptr, nullptr, nullptr,
      nullptr, nullptr, nullptr, x1, nullptr, N_NODES, 512, 512);
  bn_part_kernel<<<48, 256, 0, stream>>>(x1, part);
  bn_fin_kernel<<<1, 256, 0, stream>>>(part, g1, be1, stats1);
  bn_apply_bf_kernel<<<3072, 256, 0, stream>>>(x1, stats1, x1n);
  gemm_kernel<128, 128, 2><<<dim3(8, 48), 256, 0, stream>>>(
      x1n, bt_1, b1v, nullptr, nullptr, nullptr, nullptr, nullptr, nullptr,
      nullptr, nullptr, nullptr, nullptr, x2, N_NODES, 1024, 512);
  gemm_kernel<64, 128, 3><<<dim3(4, 96), 256, 0, stream>>>(
      x2, bt_2, b2v, nullptr, nullptr, x1, stats1, nullptr, nullptr,
      nullptr, nullptr, nullptr, out, nullptr, N_NODES, 512, 1024);
  bn_part_kernel<<<48, 256, 0, stream>>>(out, part);
  bn_fin_kernel<<<1, 256, 0, stream>>>(part, g2, be2, stats2);
  bn_apply_f32_kernel<<<3072, 256, 0, stream>>>(out, stats2);
}

// Round 2
// 160.270 us; speedup vs baseline: 1.2276x; 1.2276x over previous
//
#include <hip/hip_runtime.h>
#include <stdint.h>

// Problem constants (TransformerLayer: N=6144, D=512, B=16, NMAX=512, H=8, HD=64)
#define N_NODES 6144
#define DIM 512
#define NGRAPH 16
#define NHEAD 8
#define EPSV 1e-5f

typedef unsigned short u16;
typedef short s16x8 __attribute__((ext_vector_type(8)));
typedef __bf16 bf16x8 __attribute__((ext_vector_type(8)));
typedef float f32x4 __attribute__((ext_vector_type(4)));

__device__ __forceinline__ u16 f2bf(float f) {
  union { float f; unsigned u; } c{f};
  unsigned u = c.u;
  return (u16)((u + 0x7fffu + ((u >> 16) & 1u)) >> 16);  // RNE
}

__device__ __forceinline__ f32x4 mfma16(s16x8 a, s16x8 b, f32x4 c) {
  return __builtin_amdgcn_mfma_f32_16x16x32_bf16(
      __builtin_bit_cast(bf16x8, a), __builtin_bit_cast(bf16x8, b), c, 0, 0, 0);
}

__device__ __forceinline__ void gload_lds16(const void* g, void* l) {
  __builtin_amdgcn_global_load_lds(
      (const __attribute__((address_space(1))) unsigned int*)g,
      (__attribute__((address_space(3))) unsigned int*)l, 16, 0, 0);
}

// ---------------------------------------------------------------- starts
__global__ void starts_kernel(const int* __restrict__ batch, int* __restrict__ starts) {
  int g = threadIdx.x;
  if (g > NGRAPH) return;
  if (g == NGRAPH) { starts[g] = N_NODES; return; }
  int lo = 0, hi = N_NODES;
  while (lo < hi) { int mid = (lo + hi) >> 1; if (batch[mid] < g) lo = mid + 1; else hi = mid; }
  starts[g] = lo;
}

// ------------------------------------------------- weight transpose f32->bf16
// plain: src[R][C] f32 -> dst[C][R] bf16
__global__ void transpose_kernel(const float* __restrict__ src, u16* __restrict__ dst,
                                 int R, int C) {
  __shared__ float tile[32][33];
  int c0 = blockIdx.x * 32, r0 = blockIdx.y * 32;
  int tx = threadIdx.x & 31, ty = threadIdx.x >> 5;
#pragma unroll
  for (int i = 0; i < 32; i += 8) tile[ty + i][tx] = src[(size_t)(r0 + ty + i) * C + c0 + tx];
  __syncthreads();
#pragma unroll
  for (int i = 0; i < 32; i += 8) dst[(size_t)(c0 + ty + i) * R + r0 + tx] = f2bf(tile[tx][ty + i]);
}

// QKV: dst[v][k] = src[k][p(v)], p(v) = ((v&63)<<3)|(v>>6)   (512x512)
// i.e. dst[inv(c)][k] = src[k][c], inv(c) = ((c&7)<<6)|(c>>3)
__global__ void transpose_qkvperm_kernel(const float* __restrict__ src, u16* __restrict__ dst) {
  __shared__ float tile[32][33];
  int c0 = blockIdx.x * 32, r0 = blockIdx.y * 32;
  int tx = threadIdx.x & 31, ty = threadIdx.x >> 5;
#pragma unroll
  for (int i = 0; i < 32; i += 8) tile[ty + i][tx] = src[(size_t)(r0 + ty + i) * 512 + c0 + tx];
  __syncthreads();
#pragma unroll
  for (int i = 0; i < 32; i += 8) {
    int c = c0 + ty + i;
    int v = ((c & 7) << 6) | (c >> 3);
    dst[(size_t)v * 512 + r0 + tx] = f2bf(tile[tx][ty + i]);
  }
}

// O-proj: dst[j][c] = src[md(c)][j], md(c) = ((c&63)<<3)|(c>>6)   (512x512)
// (k-dim of bt_o permuted to match av's head-contiguous layout c = h*64+f)
__global__ void transpose_operm_kernel(const float* __restrict__ src, u16* __restrict__ dst) {
  __shared__ float tile[32][33];
  int c0 = blockIdx.x * 32, j0 = blockIdx.y * 32;
  int tx = threadIdx.x & 31, ty = threadIdx.x >> 5;
#pragma unroll
  for (int i = 0; i < 32; i += 8) {
    int c = c0 + ty + i;
    int md = ((c & 63) << 3) | (c >> 6);
    tile[ty + i][tx] = src[(size_t)md * 512 + j0 + tx];
  }
  __syncthreads();
#pragma unroll
  for (int i = 0; i < 32; i += 8)
    dst[(size_t)(j0 + ty + i) * 512 + c0 + tx] = f2bf(tile[tx][ty + i]);
}

__global__ void cvt_bf16_kernel(const float* __restrict__ src, u16* __restrict__ dst, int n4) {
  int i = blockIdx.x * 256 + threadIdx.x;
  if (i < n4) {
    float4 v = ((const float4*)src)[i];
    ushort4 o = make_ushort4(f2bf(v.x), f2bf(v.y), f2bf(v.z), f2bf(v.w));
    ((ushort4*)dst)[i] = o;
  }
}

// ---------------------------------------------------------------- GEMM
// C[i][j] = sum_k A[i][k] * Bt[j][k]   (A,Bt bf16 row-major, acc fp32)
// EPI 0: QKV -> oq/ok/ovt [node][512] row-major (col v, bias via perm)
// EPI 1: of = acc + bias + res                (fp32)
// EPI 2: ob = relu(acc + bias)                (bf16)
// EPI 3: of = acc + bias + res*st.x + st.y    (fp32, BN1-recompute residual)
template <int BM, int BN, int EPI>
__global__ __launch_bounds__(256, 2) void gemm_kernel(
    const u16* __restrict__ A, const u16* __restrict__ Bt,
    const float* __restrict__ bias0, const float* __restrict__ bias1,
    const float* __restrict__ bias2, const float* __restrict__ res,
    const float2* __restrict__ stats, u16* __restrict__ oq, u16* __restrict__ ok,
    u16* __restrict__ ovt, float* __restrict__ of, u16* __restrict__ ob,
    int M, int N, int K) {
  constexpr int NW_M = (BM >= 128) ? 2 : 1;
  constexpr int NW_N = 4 / NW_M;
  constexpr int WM = BM / NW_M, WN = BN / NW_N;
  constexpr int FM = WM / 16, FN = WN / 16;
  __shared__ __align__(16) u16 As[BM * 32];
  __shared__ __align__(16) u16 Bs[BN * 32];
  const int tid = threadIdx.x;
  const int lane = tid & 63, wv = tid >> 6;
  const int wm = wv / NW_N, wn = wv % NW_N;
  const int row0 = blockIdx.y * BM, col0 = blockIdx.x * BN;

  f32x4 acc[FM][FN] = {};
  int a_off[FM], b_off[FN];
#pragma unroll
  for (int fm = 0; fm < FM; ++fm) {
    int r = wm * WM + fm * 16 + (lane & 15);
    a_off[fm] = r * 32 + (((lane >> 4) ^ ((r >> 1) & 3)) << 3);
  }
#pragma unroll
  for (int fn = 0; fn < FN; ++fn) {
    int r = wn * WN + fn * 16 + (lane & 15);
    b_off[fn] = r * 32 + (((lane >> 4) ^ ((r >> 1) & 3)) << 3);
  }

  for (int k0 = 0; k0 < K; k0 += 32) {
    __syncthreads();
#pragma unroll
    for (int is = 0; is < BM / 64; ++is) {
      int s = is * 256 + tid;
      int r = s >> 2;
      int cl = (s & 3) ^ ((r >> 1) & 3);  // pre-swizzled source (involution)
      gload_lds16(A + (size_t)(row0 + r) * K + k0 + cl * 8,
                  (void*)(As + (size_t)(is * 256 + (tid & ~63)) * 8));
    }
#pragma unroll
    for (int is = 0; is < BN / 64; ++is) {
      int s = is * 256 + tid;
      int r = s >> 2;
      int cl = (s & 3) ^ ((r >> 1) & 3);
      gload_lds16(Bt + (size_t)(col0 + r) * K + k0 + cl * 8,
                  (void*)(Bs + (size_t)(is * 256 + (tid & ~63)) * 8));
    }
    __syncthreads();
    s16x8 af[FM], bfv[FN];
#pragma unroll
    for (int fm = 0; fm < FM; ++fm) af[fm] = *(const s16x8*)(As + a_off[fm]);
#pragma unroll
    for (int fn = 0; fn < FN; ++fn) bfv[fn] = *(const s16x8*)(Bs + b_off[fn]);
#pragma unroll
    for (int fm = 0; fm < FM; ++fm)
#pragma unroll
      for (int fn = 0; fn < FN; ++fn)
        acc[fm][fn] = mfma16(af[fm], bfv[fn], acc[fm][fn]);
  }

  // epilogue: C elem (row=(lane>>4)*4+ii, col=lane&15) per 16x16 frag
  if constexpr (EPI == 0) {
    const int which = col0 >> 9;
    u16* dst = (which == 0) ? oq : (which == 1) ? ok : ovt;
    const float* bias = (which == 0) ? bias0 : (which == 1) ? bias1 : bias2;
#pragma unroll
    for (int fn = 0; fn < FN; ++fn) {
      const int j = col0 + wn * WN + fn * 16 + (lane & 15);
      const int v = j & 511;
      const float bj = bias[((v & 63) << 3) | (v >> 6)];
#pragma unroll
      for (int fm = 0; fm < FM; ++fm) {
        const int ibase = row0 + wm * WM + fm * 16 + ((lane >> 4) << 2);
#pragma unroll
        for (int ii = 0; ii < 4; ++ii)
          dst[(size_t)(ibase + ii) * 512 + v] = f2bf(acc[fm][fn][ii] + bj);
      }
    }
  } else {
#pragma unroll
    for (int fn = 0; fn < FN; ++fn) {
      const int j = col0 + wn * WN + fn * 16 + (lane & 15);
      const float bj = bias0[j];
#pragma unroll
      for (int fm = 0; fm < FM; ++fm) {
        const int ibase = row0 + wm * WM + fm * 16 + ((lane >> 4) << 2);
        if constexpr (EPI == 1) {
#pragma unroll
          for (int ii = 0; ii < 4; ++ii) {
            int i = ibase + ii;
            of[(size_t)i * N + j] = acc[fm][fn][ii] + bj + res[(size_t)i * N + j];
          }
        } else if constexpr (EPI == 2) {
#pragma unroll
          for (int ii = 0; ii < 4; ++ii) {
            int i = ibase + ii;
            float v = acc[fm][fn][ii] + bj;
            ob[(size_t)i * N + j] = f2bf(v > 0.f ? v : 0.f);
          }
        } else {
          const float2 st = stats[j];
#pragma unroll
          for (int ii = 0; ii < 4; ++ii) {
            int i = ibase + ii;
            of[(size_t)i * N + j] = acc[fm][fn][ii] + bj + res[(size_t)i * N + j] * st.x + st.y;
          }
        }
      }
    }
  }
}

// ---------------------------------------------------------------- attention
// out[n] = sum_m exp(K[n]·Q[m]/8) V[m] / sum_m exp(...)   (per graph b, head hh)
// Scores are O(1) -> no max subtraction needed. m>=nb masked to P=0.
// q/k/v all [node][h*64+f]; output av [node][h*64+f].
__global__ __launch_bounds__(256, 2) void attn_kernel(
    const u16* __restrict__ qp, const u16* __restrict__ kp,
    const u16* __restrict__ vp, const int* __restrict__ starts,
    u16* __restrict__ av) {
  __shared__ __align__(16) u16 Qs[32 * 64];   // [m][f], 8-chunk XOR swizzle
  __shared__ __align__(16) u16 Vs[32 * 64];   // [m][f], add-rotate chunk swizzle
  __shared__ __align__(16) u16 Ps[4][512];    // per-wave P tile [16][32]
  const int idx = blockIdx.x;
  const int rb = idx & 7, hh = (idx >> 3) & 7, b = idx >> 6;
  const int base = starts[b], nb = starts[b + 1] - base;
  const int r0 = rb * 64;
  if (r0 >= nb) return;
  const int tid = threadIdx.x, lane = tid & 63, wv = tid >> 6;
  const int g = lane >> 4;
  const int rloc = r0 + wv * 16 + (lane & 15);
  const u16* krow = kp + (size_t)(base + rloc) * 512 + hh * 64 + (g << 3);
  s16x8 ak0 = *(const s16x8*)(krow);
  s16x8 ak1 = *(const s16x8*)(krow + 32);
  f32x4 acc_av[4] = {};
  float rs[4] = {0.f, 0.f, 0.f, 0.f};
  u16* Pw = Ps[wv];

  for (int m0 = 0; m0 < nb; m0 += 32) {
    __syncthreads();
    {  // stage Q tile 32x64
      int r = tid >> 3, cl = (tid & 7) ^ (r & 7);
      gload_lds16(qp + (size_t)(base + m0 + r) * 512 + hh * 64 + cl * 8,
                  (void*)(Qs + (size_t)(tid & ~63) * 8));
    }
    {  // stage V tile 32x64: physical chunk pc holds logical chunk (pc-2*(m>>3))&7
      int m = tid >> 3, pc = tid & 7;
      int c = (pc - 2 * (m >> 3)) & 7;
      gload_lds16(vp + (size_t)(base + m0 + m) * 512 + hh * 64 + c * 8,
                  (void*)(Vs + (size_t)(tid & ~63) * 8));
    }
    __syncthreads();
#pragma unroll
    for (int ch = 0; ch < 2; ++ch) {
      f32x4 s = {};
#pragma unroll
      for (int kc = 0; kc < 2; ++kc) {
        const int mr = ch * 16 + (lane & 15);
        const int chunk = kc * 4 + g;
        s16x8 bq = *(const s16x8*)(Qs + mr * 64 + ((chunk ^ (mr & 7)) << 3));
        s = mfma16(kc == 0 ? ak0 : ak1, bq, s);
      }
      const int mg = m0 + ch * 16 + (lane & 15);
      const bool valid = mg < nb;
      const int c = ch * 16 + (lane & 15);
#pragma unroll
      for (int ii = 0; ii < 4; ++ii) {
        float pv = valid ? __expf(s[ii] * 0.125f) : 0.f;
        rs[ii] += pv;
        const int r = (g << 2) + ii;
        Pw[r * 32 + (((c >> 3) ^ ((r >> 1) & 3)) << 3) + (c & 7)] = f2bf(pv);
      }
    }
    // P as A-fragment; V as natural B-fragment (lane: k=m=g*8+t, j=f=fb*16+(lane&15))
    const int pr = lane & 15;
    s16x8 pa = *(const s16x8*)(Pw + pr * 32 + ((g ^ ((pr >> 1) & 3)) << 3));
#pragma unroll
    for (int fb = 0; fb < 4; ++fb) {
      const int fl = fb * 16 + (lane & 15);
      const int off0 = (g * 8) * 64 + ((((fl >> 3) + 2 * g) & 7) << 3) + (fl & 7);
      s16x8 bv;
#pragma unroll
      for (int t = 0; t < 8; ++t) bv[t] = (short)Vs[off0 + t * 64];
      acc_av[fb] = mfma16(pa, bv, acc_av[fb]);
    }
  }
#pragma unroll
  for (int ii = 0; ii < 4; ++ii) {
    float v = rs[ii];
    v += __shfl_xor(v, 1); v += __shfl_xor(v, 2);
    v += __shfl_xor(v, 4); v += __shfl_xor(v, 8);
    rs[ii] = 1.f / v;
  }
#pragma unroll
  for (int ii = 0; ii < 4; ++ii) {
    const int rl = r0 + wv * 16 + (g << 2) + ii;
    if (rl < nb) {
      const size_t node = base + rl;
#pragma unroll
      for (int fb = 0; fb < 4; ++fb) {
        const int f = fb * 16 + (lane & 15);
        av[node * 512 + hh * 64 + f] = f2bf(acc_av[fb][ii] * rs[ii]);
      }
    }
  }
}

// ---------------------------------------------------------------- batchnorm
__global__ void bn_part_kernel(const float* __restrict__ x, float4* __restrict__ part) {
  const int p = blockIdx.x, t = threadIdx.x;
  float s0 = 0, q0 = 0, s1 = 0, q1 = 0;
  const int r0 = p * 128;
  for (int r = r0; r < r0 + 128; ++r) {
    float2 v = ((const float2*)x)[(size_t)r * 256 + t];
    s0 += v.x; q0 += v.x * v.x; s1 += v.y; q1 += v.y * v.y;
  }
  part[p * 256 + t] = make_float4(s0, q0, s1, q1);
}

__global__ void bn_fin_kernel(const float4* __restrict__ part, const float* __restrict__ g,
                              const float* __restrict__ be, float2* __restrict__ stats) {
  const int t = threadIdx.x;
  float s0 = 0, q0 = 0, s1 = 0, q1 = 0;
  for (int p = 0; p < 48; ++p) {
    float4 v = part[p * 256 + t];
    s0 += v.x; q0 += v.y; s1 += v.z; q1 += v.w;
  }
  const float inv = 1.f / (float)N_NODES;
  {
    int c = 2 * t;
    float m = s0 * inv, var = q0 * inv - m * m;
    float sc = g[c] * rsqrtf(var + EPSV);
    stats[c] = make_float2(sc, be[c] - m * sc);
  }
  {
    int c = 2 * t + 1;
    float m = s1 * inv, var = q1 * inv - m * m;
    float sc = g[c] * rsqrtf(var + EPSV);
    stats[c] = make_float2(sc, be[c] - m * sc);
  }
}

__global__ void bn_apply_bf_kernel(const float* __restrict__ x, const float2* __restrict__ stats,
                                   u16* __restrict__ o) {
  const int i = (blockIdx.x * 256 + threadIdx.x) * 4;
  float4 v = *(const float4*)(x + i);
  const int c = i & 511;
  float2 sa = stats[c], sb = stats[c + 1], sc2 = stats[c + 2], sd = stats[c + 3];
  ushort4 r = make_ushort4(f2bf(v.x * sa.x + sa.y), f2bf(v.y * sb.x + sb.y),
                           f2bf(v.z * sc2.x + sc2.y), f2bf(v.w * sd.x + sd.y));
  *(ushort4*)(o + i) = r;
}

__global__ void bn_apply_f32_kernel(float* __restrict__ x, const float2* __restrict__ stats) {
  const int i = (blockIdx.x * 256 + threadIdx.x) * 4;
  float4 v = *(float4*)(x + i);
  const int c = i & 511;
  float2 sa = stats[c], sb = stats[c + 1], sc2 = stats[c + 2], sd = stats[c + 3];
  *(float4*)(x + i) = make_float4(v.x * sa.x + sa.y, v.y * sb.x + sb.y,
                                  v.z * sc2.x + sc2.y, v.w * sd.x + sd.y);
}

// ---------------------------------------------------------------- launch
extern "C" void kernel_launch(void* const* d_in, const int* in_sizes, int n_in,
                              void* d_out, int out_size, void* d_ws, size_t ws_size,
                              hipStream_t stream) {
  const float* h   = (const float*)d_in[0];
  const int* batch = (const int*)d_in[1];
  const float* Wq = (const float*)d_in[2];  const float* bq = (const float*)d_in[3];
  const float* Wk = (const float*)d_in[4];  const float* bk = (const float*)d_in[5];
  const float* Wv = (const float*)d_in[6];  const float* bv = (const float*)d_in[7];
  const float* Wo = (const float*)d_in[8];  const float* bo = (const float*)d_in[9];
  const float* g1 = (const float*)d_in[10]; const float* be1 = (const float*)d_in[11];
  const float* W1 = (const float*)d_in[12]; const float* b1v = (const float*)d_in[13];
  const float* W2 = (const float*)d_in[14]; const float* b2v = (const float*)d_in[15];
  const float* g2 = (const float*)d_in[16]; const float* be2 = (const float*)d_in[17];
  float* out = (float*)d_out;
  (void)in_sizes; (void)n_in; (void)out_size; (void)ws_size;

  char* ws = (char*)d_ws;
  size_t off = 0;
  auto alloc = [&](size_t bytes) -> void* {
    void* p = ws + off;
    off += (bytes + 255) & ~(size_t)255;
    return p;
  };
  int*    starts = (int*)alloc(17 * 4);
  float4* part   = (float4*)alloc((size_t)48 * 256 * sizeof(float4));
  float2* stats1 = (float2*)alloc(512 * sizeof(float2));
  float2* stats2 = (float2*)alloc(512 * sizeof(float2));
  u16* bt_qkv = (u16*)alloc((size_t)1536 * 512 * 2);
  u16* bt_o   = (u16*)alloc((size_t)512 * 512 * 2);
  u16* bt_1   = (u16*)alloc((size_t)1024 * 512 * 2);
  u16* bt_2   = (u16*)alloc((size_t)512 * 1024 * 2);
  u16* A0  = (u16*)alloc((size_t)N_NODES * 512 * 2);          // h bf16; reused as av
  u16* qp  = (u16*)alloc((size_t)(N_NODES + 64) * 512 * 2);   // reused (with kp) as x2
  u16* kp  = (u16*)alloc((size_t)(N_NODES + 64) * 512 * 2);
  u16* vpb = (u16*)alloc((size_t)(N_NODES + 64) * 512 * 2);
  float* x1 = (float*)alloc((size_t)N_NODES * 512 * 4);
  u16* x1n  = (u16*)alloc((size_t)N_NODES * 512 * 2);
  u16* av = A0;
  u16* x2 = qp;  // qp+kp = 12.7MB >= 12.6MB needed

  starts_kernel<<<1, 32, 0, stream>>>(batch, starts);
  transpose_qkvperm_kernel<<<dim3(16, 16), 256, 0, stream>>>(Wq, bt_qkv);
  transpose_qkvperm_kernel<<<dim3(16, 16), 256, 0, stream>>>(Wk, bt_qkv + 512 * 512);
  transpose_qkvperm_kernel<<<dim3(16, 16), 256, 0, stream>>>(Wv, bt_qkv + 2 * 512 * 512);
  transpose_operm_kernel<<<dim3(16, 16), 256, 0, stream>>>(Wo, bt_o);
  transpose_kernel<<<dim3(32, 16), 256, 0, stream>>>(W1, bt_1, 512, 1024);
  transpose_kernel<<<dim3(16, 32), 256, 0, stream>>>(W2, bt_2, 1024, 512);
  cvt_bf16_kernel<<<3072, 256, 0, stream>>>(h, A0, N_NODES * 512 / 4);

  gemm_kernel<128, 128, 0><<<dim3(12, 48), 256, 0, stream>>>(
      A0, bt_qkv, bq, bk, bv, nullptr, nullptr, qp, kp, vpb,
      nullptr, nullptr, N_NODES, 1536, 512);
  attn_kernel<<<NGRAPH * NHEAD * 8, 256, 0, stream>>>(qp, kp, vpb, starts, av);
  gemm_kernel<64, 128, 1><<<dim3(4, 96), 256, 0, stream>>>(
      av, bt_o, bo, nullptr, nullptr, h, nullptr, nullptr, nullptr,
      nullptr, x1, nullptr, N_NODES, 512, 512);
  bn_part_kernel<<<48, 256, 0, stream>>>(x1, part);
  bn_fin_kernel<<<1, 256, 0, stream>>>(part, g1, be1, stats1);
  bn_apply_bf_kernel<<<3072, 256, 0, stream>>>(x1, stats1, x1n);
  gemm_kernel<128, 128, 2><<<dim3(8, 48), 256, 0, stream>>>(
      x1n, bt_1, b1v, nullptr, nullptr, nullptr, nullptr, nullptr, nullptr,
      nullptr, nullptr, x2, N_NODES, 1024, 512);
  gemm_kernel<64, 128, 3><<<dim3(4, 96), 256, 0, stream>>>(
      x2, bt_2, b2v, nullptr, nullptr, x1, stats1, nullptr, nullptr,
      nullptr, out, nullptr, N_NODES, 512, 1024);
  bn_part_kernel<<<48, 256, 0, stream>>>(out, part);
  bn_fin_kernel<<<1, 256, 0, stream>>>(part, g2, be2, stats2);
  bn_apply_f32_kernel<<<3072, 256, 0, stream>>>(out, stats2);
}